// Round 3
// baseline (882.026 us; speedup 1.0000x reference)
//
#include <hip/hip_runtime.h>
#include <cstddef>
#include <cstdint>

// Problem constants
constexpr int Bz = 8, CIN = 256, Hh = 96, Ww = 96;
constexpr int EMB1 = 256, EMB2 = 128, NCLS = 80;
constexpr int HP = 98; // padded spatial
constexpr size_t PIX = (size_t)Hh * Ww;                 // 9216
constexpr size_t XP_ELEMS = (size_t)Bz * HP * HP * CIN; // 19,668,992 bf16 elems

// Output layout (flat concat, fp32)
constexpr size_t O0 = 0;                       // cls_score      (B,80,96,96)
constexpr size_t O1 = (size_t)Bz * NCLS * PIX; // cls_score_neg
constexpr size_t O2 = 2 * O1;                  // distances
constexpr size_t O3 = 3 * O1;                  // distances_neg  (B,80,3,96,96)
constexpr size_t O4 = 6 * O1;                  // probs_ori

typedef short bf16x8 __attribute__((ext_vector_type(8)));
typedef float f32x4 __attribute__((ext_vector_type(4)));

__device__ inline unsigned short f2bf(float f) {
  union { float f; unsigned int u; } v; v.f = f;
  unsigned int r = v.u + 0x7fffu + ((v.u >> 16) & 1u);
  return (unsigned short)(r >> 16);
}

// ---------------------------------------------------------------------------
// Prep: x (NCHW fp32) -> padded NHWC bf16 interior (borders via memset).
// LDS transpose: coalesced 128B reads per half-wave, conflict-free LDS,
// coalesced bf16 row writes. Tile = 32 px (one row segment) x 256 ch.
__global__ __launch_bounds__(256) void pad_x_kernel(const float* __restrict__ x,
                                                    unsigned short* __restrict__ xp) {
  __shared__ float tile[32][257];
  const int b = blockIdx.z, y = blockIdx.y, x0 = blockIdx.x * 32;
  const int t = threadIdx.x;
  const int px = t & 31, cg = t >> 5;  // 8 channel groups
  const float* src = x + (((size_t)b * CIN) * Hh + y) * Ww + x0 + px;
#pragma unroll 4
  for (int c = cg; c < CIN; c += 8)
    tile[px][c] = src[(size_t)c * Hh * Ww];
  __syncthreads();
  unsigned short* orow =
      xp + (((size_t)b * HP + y + 1) * HP + (x0 + 1)) * 256 + t;
#pragma unroll 4
  for (int p = 0; p < 32; ++p)
    orow[(size_t)p * 256] = f2bf(tile[p][t]);
}

// Prep: weights -> bf16 [tap][oc][ic]; BN fold (fp32 scale/offset)
__global__ __launch_bounds__(256) void prep_w_kernel(
    const float* __restrict__ w1, const float* __restrict__ w2,
    const float* __restrict__ c1b, const float* __restrict__ g,
    const float* __restrict__ be, const float* __restrict__ mu,
    const float* __restrict__ var, unsigned short* __restrict__ wt1,
    unsigned short* __restrict__ wt2, float* __restrict__ bns,
    float* __restrict__ bno) {
  const int idx = blockIdx.x * 256 + threadIdx.x;
  if (idx < 9 * 256 * 256) {  // wt1[tap][oc][ic]
    const int ic = idx & 255, oc = (idx >> 8) & 255, tap = idx >> 16;
    wt1[idx] = f2bf(w1[((size_t)(oc * 256 + ic)) * 9 + tap]);
  }
  if (idx < 9 * 128 * 256) {  // wt2[tap][oc][ic]
    const int ic = idx & 255, oc = (idx >> 8) & 127, tap = idx >> 15;
    wt2[idx] = f2bf(w2[((size_t)(oc * 256 + ic)) * 9 + tap]);
  }
  if (idx < 256) {
    const float s = g[idx] * rsqrtf(var[idx] + 1e-5f);
    bns[idx] = s;
    bno[idx] = (c1b[idx] - mu[idx]) * s + be[idx];
  }
}

// reps = l2norm(rep_w[:,0] + rep_b) per class (80 x 128); fp32 rpv + bf16 Rb
__global__ __launch_bounds__(128) void rep_norm_kernel(const float* __restrict__ rw,
                                                       const float* __restrict__ rb,
                                                       float* __restrict__ r,
                                                       unsigned short* __restrict__ Rb) {
  __shared__ float red[2];
  const int c = blockIdx.x, t = threadIdx.x;
  const float v = rw[c * 128 + t] + rb[c * 128 + t];
  float s = v * v;
  for (int msk = 1; msk < 64; msk <<= 1) s += __shfl_xor(s, msk, 64);
  if ((t & 63) == 0) red[t >> 6] = s;
  __syncthreads();
  const float ss = red[0] + red[1];
  const float rn = 1.f / fmaxf(sqrtf(ss), 1e-12f);
  r[c * 128 + t] = v * rn;
  Rb[(size_t)(c * 4) * 128 + t] = f2bf(v * rn);  // rep slot v=0 (positive)
}

// reps_neg: per (class, neg) 3-layer MLP on r, then l2norm -> bf16 Rb slot
__global__ __launch_bounds__(128) void mlp_neg_kernel(const float* __restrict__ r,
                                                      const float* __restrict__ W,
                                                      const float* __restrict__ bb,
                                                      unsigned short* __restrict__ Rb) {
  __shared__ float h0[128], h1[128];
  __shared__ float red[2];
  const int c = blockIdx.x, ng = blockIdx.y, t = threadIdx.x;
  h0[t] = r[c * 128 + t];
  __syncthreads();
  float s = 0.f;
  for (int lay = 0; lay < 3; ++lay) {
    const float* hin = (lay & 1) ? h1 : h0;
    float* hout = (lay & 1) ? h0 : h1;
    const float* wr = W + (((size_t)ng * 3 + lay) * 128 + t) * 128;
    s = bb[(ng * 3 + lay) * 128 + t];
    for (int e = 0; e < 128; ++e) s += wr[e] * hin[e];
    if (lay < 2) hout[t] = fmaxf(s, 0.f);
    __syncthreads();
  }
  float q = s * s;
  for (int msk = 1; msk < 64; msk <<= 1) q += __shfl_xor(q, msk, 64);
  if ((t & 63) == 0) red[t >> 6] = q;
  __syncthreads();
  const float ss = red[0] + red[1];
  const float rn = 1.f / fmaxf(sqrtf(ss), 1e-12f);
  Rb[((size_t)(c * 4) + 1 + ng) * 128 + t] = f2bf(s * rn);
}

// ---------------------------------------------------------------------------
// bf16 MFMA implicit-GEMM 3x3 conv, NHWC (padded input HPxHP, IC=256).
// DIRECT-TO-REGISTER version: no LDS staging, no barriers in the K-loop.
// Each MFMA fragment is loaded straight from global (L1/L2-resident):
// lane(quad,col) of fragment mt needs (row=col, k-chunk=quad) ->
// addr = uniform_base + col*512B + quad*16B. Uniform bases are forced to
// SGPRs via readfirstlane so loads compile to saddr + v_off + imm.
// A-data/block ~92KB (L1/L2, 9x tap reuse); B (weights) 1.2MB shared by all
// blocks (L2). Block tile: 128 px (8 rows x 16 cols) x 128 oc; 4 waves,
// each 64x64 via 4x4 mfma_f32_16x16x32_bf16.
// BN=true: out bf16 padded NHWC (B,98,98,256) at (y+1,x+1), v=acc*e0+e1
// BN=false: out bf16 NHWC (B,96,96,128), v=l2norm_c(acc+e0) (fused l2norm)
template <int OC, bool BN>
__device__ __forceinline__ void conv3x3_body(
    const unsigned short* __restrict__ in, const unsigned short* __restrict__ wt,
    const float* __restrict__ e0, const float* __restrict__ e1,
    unsigned short* __restrict__ out16) {
  __shared__ float nrm[128][2];  // fused l2norm partials (BN=false only)
  const int tile = blockIdx.x;   // 0..71
  const int oc0 = blockIdx.y * 128;
  const int b = blockIdx.z;
  const int ty = (tile / 6) * 8, tx = (tile % 6) * 16;
  const int t = threadIdx.x;
  const int lane = t & 63, w = t >> 6;
  const int wm = w & 1, wn = w >> 1;
  const int quad = lane >> 4, col = lane & 15;

  // per-lane fragment offset (elems): col px-steps (stride 256ch) + quad k-chunk
  const int laneO = col * 256 + quad * 8;

  f32x4 acc[4][4];
#pragma unroll
  for (int mt = 0; mt < 4; ++mt)
#pragma unroll
    for (int nt = 0; nt < 4; ++nt) acc[mt][nt] = {0.f, 0.f, 0.f, 0.f};

  for (int tap = 0; tap < 9; ++tap) {
    const int ky = tap / 3, kx = tap % 3;
    // wave-uniform base offsets -> SGPR via readfirstlane
    int uA[4], uB[4];
#pragma unroll
    for (int mt = 0; mt < 4; ++mt)
      uA[mt] = __builtin_amdgcn_readfirstlane(
          (int)((((b * HP) + ty + wm * 4 + mt + ky) * HP + tx + kx) * 256));
#pragma unroll
    for (int nt = 0; nt < 4; ++nt)
      uB[nt] = __builtin_amdgcn_readfirstlane(
          (tap * OC + oc0 + wn * 64 + nt * 16) * 256);
#pragma unroll
    for (int c8 = 0; c8 < 8; ++c8) {
      const int ch0 = c8 * 32;  // channel offset (elems), folds into offset:N
      bf16x8 af[4], bf[4];
#pragma unroll
      for (int mt = 0; mt < 4; ++mt)
        af[mt] = *(const bf16x8*)(in + uA[mt] + laneO + ch0);
#pragma unroll
      for (int nt = 0; nt < 4; ++nt)
        bf[nt] = *(const bf16x8*)(wt + uB[nt] + laneO + ch0);
#pragma unroll
      for (int mt = 0; mt < 4; ++mt)
#pragma unroll
        for (int nt = 0; nt < 4; ++nt)
          acc[mt][nt] = __builtin_amdgcn_mfma_f32_16x16x32_bf16(
              af[mt], bf[nt], acc[mt][nt], 0, 0, 0);
    }
  }

  // epilogue
  float sc[4], of[4];
#pragma unroll
  for (int nt = 0; nt < 4; ++nt) {
    const int oc = oc0 + wn * 64 + nt * 16 + col;
    sc[nt] = e0[oc];
    of[nt] = BN ? e1[oc] : 0.f;
  }
  if (BN) {
#pragma unroll
    for (int mt = 0; mt < 4; ++mt)
#pragma unroll
      for (int r = 0; r < 4; ++r) {
        const int px = wm * 64 + mt * 16 + quad * 4 + r;
        const int y = ty + (px >> 4), x = tx + (px & 15);
        unsigned short* rowp =
            out16 + (((size_t)b * HP + y + 1) * HP + x + 1) * 256 + oc0 + wn * 64 + col;
#pragma unroll
        for (int nt = 0; nt < 4; ++nt)
          rowp[nt * 16] = f2bf(acc[mt][nt][r] * sc[nt] + of[nt]);
      }
  } else {
    // fused channel l2norm: this block owns ALL 128 output channels per px
    float part[4][4];
#pragma unroll
    for (int mt = 0; mt < 4; ++mt)
#pragma unroll
      for (int r = 0; r < 4; ++r) {
        float s = 0.f;
#pragma unroll
        for (int nt = 0; nt < 4; ++nt) {
          const float v = acc[mt][nt][r] + sc[nt];
          s += v * v;
        }
        part[mt][r] = s;
      }
#pragma unroll
    for (int msk = 1; msk < 16; msk <<= 1)
#pragma unroll
      for (int mt = 0; mt < 4; ++mt)
#pragma unroll
        for (int r = 0; r < 4; ++r)
          part[mt][r] += __shfl_xor(part[mt][r], msk, 64);
    if (col == 0) {
#pragma unroll
      for (int mt = 0; mt < 4; ++mt)
#pragma unroll
        for (int r = 0; r < 4; ++r)
          nrm[wm * 64 + mt * 16 + quad * 4 + r][wn] = part[mt][r];
    }
    __syncthreads();
#pragma unroll
    for (int mt = 0; mt < 4; ++mt)
#pragma unroll
      for (int r = 0; r < 4; ++r) {
        const int px = wm * 64 + mt * 16 + quad * 4 + r;
        const int y = ty + (px >> 4), x = tx + (px & 15);
        const float nn = nrm[px][0] + nrm[px][1];
        const float rn = 1.f / fmaxf(sqrtf(nn), 1e-12f);
        unsigned short* rowp =
            out16 + (((size_t)b * Hh + y) * Ww + x) * 128 + wn * 64 + col;
#pragma unroll
        for (int nt = 0; nt < 4; ++nt)
          rowp[nt * 16] = f2bf((acc[mt][nt][r] + sc[nt]) * rn);
      }
  }
}

// distinct names so rocprof rows distinguish conv1 vs conv2
__global__ __launch_bounds__(256) void conv1_mfma(
    const unsigned short* __restrict__ in, const unsigned short* __restrict__ wt,
    const float* __restrict__ e0, const float* __restrict__ e1,
    unsigned short* __restrict__ out16) {
  conv3x3_body<256, true>(in, wt, e0, e1, out16);
}
__global__ __launch_bounds__(256) void conv2_mfma(
    const unsigned short* __restrict__ in, const unsigned short* __restrict__ wt,
    const float* __restrict__ e0, const float* __restrict__ e1,
    unsigned short* __restrict__ out16) {
  conv3x3_body<128, false>(in, wt, e0, e1, out16);
}

// ---------------------------------------------------------------------------
// 4x4 transpose across lanes differing in bits 0..1 (regs r0..r3)
__device__ inline void xpose4(float& r0, float& r1, float& r2, float& r3,
                              int lane) {
  const int b1 = (lane >> 1) & 1, b0 = lane & 1;
  float s0 = b1 ? r0 : r2;
  float s1 = b1 ? r1 : r3;
  s0 = __shfl_xor(s0, 2, 64);
  s1 = __shfl_xor(s1, 2, 64);
  if (b1) { r0 = s0; r1 = s1; } else { r2 = s0; r3 = s1; }
  float t0 = b0 ? r0 : r1;
  float t1 = b0 ? r2 : r3;
  t0 = __shfl_xor(t0, 1, 64);
  t1 = __shfl_xor(t1, 1, 64);
  if (b0) { r0 = t0; r2 = t1; } else { r1 = t0; r3 = t1; }
}

// Score: MFMA GEMM (64 px x 320 reps, K=128) + fused epilogue, no LDS.
// Rep order: n = cls*4 + {pos, neg0, neg1, neg2}. Wave w covers n in
// [w*80, w*80+80) as 5 n-tiles of 16.
__global__ __launch_bounds__(256) void score_mfma(
    const unsigned short* __restrict__ embb, const unsigned short* __restrict__ Rb,
    float* __restrict__ out) {
  const int px0 = blockIdx.x * 64;
  const int b = blockIdx.y;
  const int t = threadIdx.x;
  const int lane = t & 63, w = t >> 6;
  const int quad = lane >> 4, col = lane & 15;
  const int n0 = w * 80;
  const unsigned short* Abase = embb + ((size_t)b * PIX + px0) * 128;

  f32x4 acc[4][5];
#pragma unroll
  for (int mt = 0; mt < 4; ++mt)
#pragma unroll
    for (int nt = 0; nt < 5; ++nt) acc[mt][nt] = {0.f, 0.f, 0.f, 0.f};

#pragma unroll
  for (int ks = 0; ks < 4; ++ks) {
    bf16x8 bf[5], af[4];
#pragma unroll
    for (int nt = 0; nt < 5; ++nt)
      bf[nt] = *(const bf16x8*)(Rb + (size_t)(n0 + nt * 16 + col) * 128 +
                                ks * 32 + quad * 8);
#pragma unroll
    for (int mt = 0; mt < 4; ++mt)
      af[mt] = *(const bf16x8*)(Abase + (size_t)(mt * 16 + col) * 128 +
                                ks * 32 + quad * 8);
#pragma unroll
    for (int mt = 0; mt < 4; ++mt)
#pragma unroll
      for (int nt = 0; nt < 5; ++nt)
        acc[mt][nt] = __builtin_amdgcn_mfma_f32_16x16x32_bf16(
            af[mt], bf[nt], acc[mt][nt], 0, 0, 0);
  }

  const int j = lane & 3, kq = (lane >> 2) & 3;
#pragma unroll
  for (int mt = 0; mt < 4; ++mt) {
    const int px = px0 + mt * 16 + quad * 4 + j;
#pragma unroll
    for (int nt = 0; nt < 5; ++nt) {
      float v0 = acc[mt][nt][0], v1 = acc[mt][nt][1];
      float v2 = acc[mt][nt][2], v3 = acc[mt][nt][3];
      xpose4(v0, v1, v2, v3, lane);
      // lane now holds (dp, dn0, dn1, dn2) for (px, cls)
      const int gc = w * 20 + nt * 4 + kq;
      const float d2p = fmaxf(2.f - 2.f * v0, 0.f);
      const float dist = sqrtf(d2p);
      const float q0 = fmaxf(2.f - 2.f * v1, 0.f);
      const float q1 = fmaxf(2.f - 2.f * v2, 0.f);
      const float q2 = fmaxf(2.f - 2.f * v3, 0.f);
      const float dn0 = sqrtf(q0), dn1 = sqrtf(q1), dn2 = sqrtf(q2);
      const float pn = __expf(-2.f * fminf(q0, fminf(q1, q2)));
      const float pori = __expf(-2.f * d2p);
      const float minn = fminf(dn0, fminf(dn1, dn2));
      const float shifted = dist + 0.3f * fmaxf(2.0f - minn, 0.f);
      const float p = __expf(-2.f * shifted * shifted);
      const float clsv = __logf(fmaxf(p, 1e-5f) / fmaxf(1.f - p, 1e-5f));
      const size_t bc = ((size_t)b * NCLS + gc) * PIX + px;
      out[O0 + bc] = clsv;
      out[O1 + bc] = pn;
      out[O2 + bc] = dist;
      out[O4 + bc] = pori;
      const size_t b3 = (((size_t)b * NCLS + gc) * 3) * PIX + px;
      out[O3 + b3] = dn0;
      out[O3 + b3 + PIX] = dn1;
      out[O3 + b3 + 2 * PIX] = dn2;
    }
  }
}

// ---------------------------------------------------------------------------
extern "C" void kernel_launch(void* const* d_in, const int* in_sizes, int n_in,
                              void* d_out, int out_size, void* d_ws,
                              size_t ws_size, hipStream_t stream) {
  const float* x = (const float*)d_in[0];
  const float* w1 = (const float*)d_in[1];
  const float* c1b = (const float*)d_in[2];
  const float* g = (const float*)d_in[3];
  const float* be = (const float*)d_in[4];
  const float* mu = (const float*)d_in[5];
  const float* var = (const float*)d_in[6];
  const float* w2 = (const float*)d_in[7];
  const float* c2b = (const float*)d_in[8];
  const float* rw = (const float*)d_in[9];
  const float* rb = (const float*)d_in[10];
  const float* nw = (const float*)d_in[11];
  const float* nb = (const float*)d_in[12];
  float* out = (float*)d_out;

  unsigned short* xp = (unsigned short*)d_ws;   // bf16 padded NHWC input
  unsigned short* hp = xp + XP_ELEMS;           // bf16 padded NHWC hidden
  unsigned short* wt1 = hp + XP_ELEMS;          // 589,824 bf16
  unsigned short* wt2 = wt1 + 589824;           // 294,912 bf16
  float* bns = (float*)(wt2 + 294912);
  float* bno = bns + 256;
  float* rpv = bno + 256;                       // 10,240 fp32
  unsigned short* Rb = (unsigned short*)(rpv + 10240);  // 40,960 bf16
  unsigned short* embb = xp;                    // alias: xp dead after conv1

  hipMemsetAsync(xp, 0, XP_ELEMS * sizeof(unsigned short), stream);
  hipMemsetAsync(hp, 0, XP_ELEMS * sizeof(unsigned short), stream);
  pad_x_kernel<<<dim3(3, Hh, Bz), 256, 0, stream>>>(x, xp);
  prep_w_kernel<<<2304, 256, 0, stream>>>(w1, w2, c1b, g, be, mu, var, wt1, wt2,
                                          bns, bno);
  rep_norm_kernel<<<NCLS, 128, 0, stream>>>(rw, rb, rpv, Rb);
  mlp_neg_kernel<<<dim3(NCLS, 3), 128, 0, stream>>>(rpv, nw, nb, Rb);
  conv1_mfma<<<dim3(72, 2, Bz), 256, 0, stream>>>(xp, wt1, bns, bno, hp);
  conv2_mfma<<<dim3(72, 1, Bz), 256, 0, stream>>>(hp, wt2, c2b, nullptr, embb);
  score_mfma<<<dim3(144, Bz), 256, 0, stream>>>(embb, Rb, out);
}

// Round 6
// 562.559 us; speedup vs baseline: 1.5679x; 1.5679x over previous
//
#include <hip/hip_runtime.h>
#include <cstddef>
#include <cstdint>

// Problem constants
constexpr int Bz = 8, CIN = 256, Hh = 96, Ww = 96;
constexpr int EMB1 = 256, EMB2 = 128, NCLS = 80;
constexpr int HP = 98; // padded spatial
constexpr size_t PIX = (size_t)Hh * Ww;                 // 9216
constexpr size_t XP_ELEMS = (size_t)Bz * HP * HP * CIN; // 19,668,992 bf16 elems

// Output layout (flat concat, fp32)
constexpr size_t O0 = 0;                       // cls_score      (B,80,96,96)
constexpr size_t O1 = (size_t)Bz * NCLS * PIX; // cls_score_neg
constexpr size_t O2 = 2 * O1;                  // distances
constexpr size_t O3 = 3 * O1;                  // distances_neg  (B,80,3,96,96)
constexpr size_t O4 = 6 * O1;                  // probs_ori

typedef short bf16x8 __attribute__((ext_vector_type(8)));
typedef float f32x4 __attribute__((ext_vector_type(4)));

__device__ inline unsigned short f2bf(float f) {
  union { float f; unsigned int u; } v; v.f = f;
  unsigned int r = v.u + 0x7fffu + ((v.u >> 16) & 1u);
  return (unsigned short)(r >> 16);
}

// async global->LDS, 16B per lane. OFFSET ARG MUST BE 0: the imm offset of
// LDS-DMA instructions participates in the LDS destination address (not just
// the global address) — nonzero values corrupted LDS in R4/R5. All address
// offsets go into the global POINTER (the R0/R2-proven pattern).
#define GLD16(gp, lp)                                              \
  __builtin_amdgcn_global_load_lds(                                \
      (__attribute__((address_space(1))) void*)((void*)(gp)),      \
      (__attribute__((address_space(3))) void*)(lp), 16, 0, 0)

// Counted-wait + barrier as ONE asm with memory clobber (raw s_barrier is
// not a compiler fence); sched_barrier(0) pins the MIR scheduler.
#define WAIT_BAR(n)                                                       \
  do {                                                                    \
    asm volatile("s_waitcnt vmcnt(" #n ")\n\ts_barrier" ::: "memory");    \
    __builtin_amdgcn_sched_barrier(0);                                    \
  } while (0)

// ---------------------------------------------------------------------------
// Prep: x (NCHW fp32) -> padded NHWC bf16 interior (borders via memset).
__global__ __launch_bounds__(256) void pad_x_kernel(const float* __restrict__ x,
                                                    unsigned short* __restrict__ xp) {
  __shared__ float tile[32][257];
  const int b = blockIdx.z, y = blockIdx.y, x0 = blockIdx.x * 32;
  const int t = threadIdx.x;
  const int px = t & 31, cg = t >> 5;  // 8 channel groups
  const float* src = x + (((size_t)b * CIN) * Hh + y) * Ww + x0 + px;
#pragma unroll 4
  for (int c = cg; c < CIN; c += 8)
    tile[px][c] = src[(size_t)c * Hh * Ww];
  __syncthreads();
  unsigned short* orow =
      xp + (((size_t)b * HP + y + 1) * HP + (x0 + 1)) * 256 + t;
#pragma unroll 4
  for (int p = 0; p < 32; ++p)
    orow[(size_t)p * 256] = f2bf(tile[p][t]);
}

// Prep: weights -> bf16 [tap][oc][ic]; BN fold (fp32 scale/offset)
__global__ __launch_bounds__(256) void prep_w_kernel(
    const float* __restrict__ w1, const float* __restrict__ w2,
    const float* __restrict__ c1b, const float* __restrict__ g,
    const float* __restrict__ be, const float* __restrict__ mu,
    const float* __restrict__ var, unsigned short* __restrict__ wt1,
    unsigned short* __restrict__ wt2, float* __restrict__ bns,
    float* __restrict__ bno) {
  const int idx = blockIdx.x * 256 + threadIdx.x;
  if (idx < 9 * 256 * 256) {  // wt1[tap][oc][ic]
    const int ic = idx & 255, oc = (idx >> 8) & 255, tap = idx >> 16;
    wt1[idx] = f2bf(w1[((size_t)(oc * 256 + ic)) * 9 + tap]);
  }
  if (idx < 9 * 128 * 256) {  // wt2[tap][oc][ic]
    const int ic = idx & 255, oc = (idx >> 8) & 127, tap = idx >> 15;
    wt2[idx] = f2bf(w2[((size_t)(oc * 256 + ic)) * 9 + tap]);
  }
  if (idx < 256) {
    const float s = g[idx] * rsqrtf(var[idx] + 1e-5f);
    bns[idx] = s;
    bno[idx] = (c1b[idx] - mu[idx]) * s + be[idx];
  }
}

// reps = l2norm(rep_w[:,0] + rep_b) per class (80 x 128); fp32 rpv + bf16 Rb
__global__ __launch_bounds__(128) void rep_norm_kernel(const float* __restrict__ rw,
                                                       const float* __restrict__ rb,
                                                       float* __restrict__ r,
                                                       unsigned short* __restrict__ Rb) {
  __shared__ float red[2];
  const int c = blockIdx.x, t = threadIdx.x;
  const float v = rw[c * 128 + t] + rb[c * 128 + t];
  float s = v * v;
  for (int msk = 1; msk < 64; msk <<= 1) s += __shfl_xor(s, msk, 64);
  if ((t & 63) == 0) red[t >> 6] = s;
  __syncthreads();
  const float ss = red[0] + red[1];
  const float rn = 1.f / fmaxf(sqrtf(ss), 1e-12f);
  r[c * 128 + t] = v * rn;
  Rb[(size_t)(c * 4) * 128 + t] = f2bf(v * rn);  // rep slot v=0 (positive)
}

// reps_neg: per (class, neg) 3-layer MLP on r, then l2norm -> bf16 Rb slot
__global__ __launch_bounds__(128) void mlp_neg_kernel(const float* __restrict__ r,
                                                      const float* __restrict__ W,
                                                      const float* __restrict__ bb,
                                                      unsigned short* __restrict__ Rb) {
  __shared__ float h0[128], h1[128];
  __shared__ float red[2];
  const int c = blockIdx.x, ng = blockIdx.y, t = threadIdx.x;
  h0[t] = r[c * 128 + t];
  __syncthreads();
  float s = 0.f;
  for (int lay = 0; lay < 3; ++lay) {
    const float* hin = (lay & 1) ? h1 : h0;
    float* hout = (lay & 1) ? h0 : h1;
    const float* wr = W + (((size_t)ng * 3 + lay) * 128 + t) * 128;
    s = bb[(ng * 3 + lay) * 128 + t];
    for (int e = 0; e < 128; ++e) s += wr[e] * hin[e];
    if (lay < 2) hout[t] = fmaxf(s, 0.f);
    __syncthreads();
  }
  float q = s * s;
  for (int msk = 1; msk < 64; msk <<= 1) q += __shfl_xor(q, msk, 64);
  if ((t & 63) == 0) red[t >> 6] = q;
  __syncthreads();
  const float ss = red[0] + red[1];
  const float rn = 1.f / fmaxf(sqrtf(ss), 1e-12f);
  Rb[((size_t)(c * 4) + 1 + ng) * 128 + t] = f2bf(s * rn);
}

// ---------------------------------------------------------------------------
// bf16 MFMA implicit-GEMM 3x3 conv, NHWC (padded input HPxHP, IC=256).
// 3-buffer LDS ring + counted vmcnt pipeline (T3/T4):
//   step u (0..71): [vmcnt(4)+s_barrier (fused asm); stage(u+2)->buf[(u+2)%3];
//                    compute buf[u%3]]
// vmcnt(4) leaves stage(u+1)'s 4 loads in flight across the barrier (never
// drain to 0 in the loop). 3 ky-rows x 24 unrolled steps; ALL step offsets
// are folded into the global POINTERS (intrinsic offset arg stays 0 —
// nonzero corrupts the LDS destination, the R4/R5 bug).
// Safety: each wave waits ITS stage(u) (vmcnt<=4) BEFORE the barrier, so
// after barrier(u) all waves' stage(u) writes are in LDS; stage(u+2)
// overwrites buf[(u-1)%3], whose readers all retired before barrier(u).
// BN=true: out bf16 padded NHWC (B,98,98,256) at (y+1,x+1), v=acc*e0+e1
// BN=false: out bf16 NHWC (B,96,96,128), v=l2norm_c(acc+e0) (fused l2norm)
template <int OC, bool BN>
__device__ __forceinline__ void conv3x3_body(
    const unsigned short* __restrict__ in, const unsigned short* __restrict__ wt,
    const float* __restrict__ e0, const float* __restrict__ e1,
    unsigned short* __restrict__ out16) {
  __shared__ unsigned short smA[3][128 * 32];  // 3 x 8KB [px][k]
  __shared__ unsigned short smB[3][128 * 32];  // 3 x 8KB [oc][k]
  __shared__ float nrm[128][2];                // l2norm partials (BN=false)
  const int tile = blockIdx.x;                 // 0..71
  const int oc0 = blockIdx.y * 128;
  const int b = blockIdx.z;
  const int ty = (tile / 6) * 8, tx = (tile % 6) * 16;
  const int t = threadIdx.x;
  const int lane = t & 63, w = t >> 6;
  const int wm = w & 1, wn = w >> 1;
  const int quad = lane >> 4, col = lane & 15;
  const int chl = (lane & 3) * 8;              // staging channel sub-offset

  // per-lane staging bases (ky=0, kx=0, ch=0)
  size_t baseA0, baseA1, baseB0, baseB1;
  {
    const int px0 = (w * 2 + 0) * 16 + (lane >> 2);
    const int px1 = (w * 2 + 1) * 16 + (lane >> 2);
    baseA0 = (((size_t)b * HP + ty + (px0 >> 4)) * HP + tx + (px0 & 15)) * 256 + chl;
    baseA1 = (((size_t)b * HP + ty + (px1 >> 4)) * HP + tx + (px1 & 15)) * 256 + chl;
    baseB0 = (size_t)(oc0 + (w * 2 + 0) * 16 + (lane >> 2)) * 256 + chl;
    baseB1 = (size_t)(oc0 + (w * 2 + 1) * 16 + (lane >> 2)) * 256 + chl;
  }

  // wave-uniform LDS staging destinations
  char* const dA0 = (char*)smA + (w * 2 + 0) * 1024;
  char* const dA1 = (char*)smA + (w * 2 + 1) * 1024;
  char* const dB0 = (char*)smB + (w * 2 + 0) * 1024;
  char* const dB1 = (char*)smB + (w * 2 + 1) * 1024;
  // per-lane LDS read bases (fragment layout)
  const char* const ldsA = (const char*)smA + (wm * 64 + col) * 64 + quad * 16;
  const char* const ldsB = (const char*)smB + (wn * 64 + col) * 64 + quad * 16;

  f32x4 acc[4][4];
#pragma unroll
  for (int mt = 0; mt < 4; ++mt)
#pragma unroll
    for (int nt = 0; nt < 4; ++nt) acc[mt][nt] = {0.f, 0.f, 0.f, 0.f};

// offsets in ELEMENTS, folded into the global pointers; intrinsic offset = 0
#define STAGE(A0p, A1p, B0p, B1p, AOFF, BOFF, BUF)        \
  do {                                                    \
    GLD16((A0p) + (AOFF), dA0 + (BUF) * 8192);            \
    GLD16((A1p) + (AOFF), dA1 + (BUF) * 8192);            \
    GLD16((B0p) + (BOFF), dB0 + (BUF) * 8192);            \
    GLD16((B1p) + (BOFF), dB1 + (BUF) * 8192);            \
  } while (0)

#define COMPUTE(BUF)                                                         \
  do {                                                                       \
    bf16x8 af0 = *(const bf16x8*)(ldsA + (BUF) * 8192 + 0);                  \
    bf16x8 af1 = *(const bf16x8*)(ldsA + (BUF) * 8192 + 1024);               \
    bf16x8 af2 = *(const bf16x8*)(ldsA + (BUF) * 8192 + 2048);               \
    bf16x8 af3 = *(const bf16x8*)(ldsA + (BUF) * 8192 + 3072);               \
    bf16x8 bf0 = *(const bf16x8*)(ldsB + (BUF) * 8192 + 0);                  \
    bf16x8 bf1 = *(const bf16x8*)(ldsB + (BUF) * 8192 + 1024);               \
    bf16x8 bf2 = *(const bf16x8*)(ldsB + (BUF) * 8192 + 2048);               \
    bf16x8 bf3 = *(const bf16x8*)(ldsB + (BUF) * 8192 + 3072);               \
    __builtin_amdgcn_s_setprio(1);                                           \
    acc[0][0] = __builtin_amdgcn_mfma_f32_16x16x32_bf16(af0, bf0, acc[0][0], 0, 0, 0); \
    acc[0][1] = __builtin_amdgcn_mfma_f32_16x16x32_bf16(af0, bf1, acc[0][1], 0, 0, 0); \
    acc[0][2] = __builtin_amdgcn_mfma_f32_16x16x32_bf16(af0, bf2, acc[0][2], 0, 0, 0); \
    acc[0][3] = __builtin_amdgcn_mfma_f32_16x16x32_bf16(af0, bf3, acc[0][3], 0, 0, 0); \
    acc[1][0] = __builtin_amdgcn_mfma_f32_16x16x32_bf16(af1, bf0, acc[1][0], 0, 0, 0); \
    acc[1][1] = __builtin_amdgcn_mfma_f32_16x16x32_bf16(af1, bf1, acc[1][1], 0, 0, 0); \
    acc[1][2] = __builtin_amdgcn_mfma_f32_16x16x32_bf16(af1, bf2, acc[1][2], 0, 0, 0); \
    acc[1][3] = __builtin_amdgcn_mfma_f32_16x16x32_bf16(af1, bf3, acc[1][3], 0, 0, 0); \
    acc[2][0] = __builtin_amdgcn_mfma_f32_16x16x32_bf16(af2, bf0, acc[2][0], 0, 0, 0); \
    acc[2][1] = __builtin_amdgcn_mfma_f32_16x16x32_bf16(af2, bf1, acc[2][1], 0, 0, 0); \
    acc[2][2] = __builtin_amdgcn_mfma_f32_16x16x32_bf16(af2, bf2, acc[2][2], 0, 0, 0); \
    acc[2][3] = __builtin_amdgcn_mfma_f32_16x16x32_bf16(af2, bf3, acc[2][3], 0, 0, 0); \
    acc[3][0] = __builtin_amdgcn_mfma_f32_16x16x32_bf16(af3, bf0, acc[3][0], 0, 0, 0); \
    acc[3][1] = __builtin_amdgcn_mfma_f32_16x16x32_bf16(af3, bf1, acc[3][1], 0, 0, 0); \
    acc[3][2] = __builtin_amdgcn_mfma_f32_16x16x32_bf16(af3, bf2, acc[3][2], 0, 0, 0); \
    acc[3][3] = __builtin_amdgcn_mfma_f32_16x16x32_bf16(af3, bf3, acc[3][3], 0, 0, 0); \
    __builtin_amdgcn_s_setprio(0);                                           \
  } while (0)

// step R in [0,22): stage step R+2 from current-row bases
#define BSEL0(J) ((J) == 0 ? Bc00 : (J) == 1 ? Bc10 : Bc20)
#define BSEL1(J) ((J) == 0 ? Bc01 : (J) == 1 ? Bc11 : Bc21)
#define STEP_MAIN(R)                                                    \
  do {                                                                  \
    WAIT_BAR(4);                                                        \
    STAGE(Acur0, Acur1, BSEL0((R + 2) / 8), BSEL1((R + 2) / 8),         \
          (R + 2) * 32, ((R + 2) % 8) * 32, (R + 2) % 3);               \
    COMPUTE((R) % 3);                                                   \
  } while (0)
// steps 22,23: prefetch next ky-row (steps 0,1 of next row)
#define STEP_PRE(R)                                                     \
  do {                                                                  \
    if ((R) == 23 && ky == 2) { WAIT_BAR(0); } else { WAIT_BAR(4); }    \
    if (ky < 2)                                                         \
      STAGE(An0, An1, Bn00, Bn01, ((R) - 22) * 32, ((R) - 22) * 32,     \
            (R + 2) % 3);                                               \
    COMPUTE((R) % 3);                                                   \
  } while (0)

  // pointer init (ky = 0)
  const unsigned short* Acur0 = in + baseA0;
  const unsigned short* Acur1 = in + baseA1;
  const unsigned short* An0 = Acur0 + HP * 256;
  const unsigned short* An1 = Acur1 + HP * 256;
  const unsigned short* Bc00 = wt + baseB0;
  const unsigned short* Bc01 = wt + baseB1;
  const unsigned short* Bc10 = Bc00 + OC * 256;
  const unsigned short* Bc11 = Bc01 + OC * 256;
  const unsigned short* Bc20 = Bc10 + OC * 256;
  const unsigned short* Bc21 = Bc11 + OC * 256;
  const unsigned short* Bn00 = Bc00 + 3 * OC * 256;
  const unsigned short* Bn01 = Bc01 + 3 * OC * 256;

  // prologue: stage steps 0,1
  STAGE(Acur0, Acur1, Bc00, Bc01, 0, 0, 0);
  STAGE(Acur0, Acur1, Bc00, Bc01, 32, 32, 1);

  for (int ky = 0; ky < 3; ++ky) {
    STEP_MAIN(0);  STEP_MAIN(1);  STEP_MAIN(2);  STEP_MAIN(3);
    STEP_MAIN(4);  STEP_MAIN(5);  STEP_MAIN(6);  STEP_MAIN(7);
    STEP_MAIN(8);  STEP_MAIN(9);  STEP_MAIN(10); STEP_MAIN(11);
    STEP_MAIN(12); STEP_MAIN(13); STEP_MAIN(14); STEP_MAIN(15);
    STEP_MAIN(16); STEP_MAIN(17); STEP_MAIN(18); STEP_MAIN(19);
    STEP_MAIN(20); STEP_MAIN(21);
    STEP_PRE(22);  STEP_PRE(23);
    if (ky < 2) {
      Acur0 = An0; Acur1 = An1;
      An0 += HP * 256; An1 += HP * 256;
      Bc00 = Bn00; Bc01 = Bn01;
      Bc10 = Bc00 + OC * 256; Bc11 = Bc01 + OC * 256;
      Bc20 = Bc10 + OC * 256; Bc21 = Bc11 + OC * 256;
      Bn00 += 3 * OC * 256; Bn01 += 3 * OC * 256;
    }
  }
#undef STEP_MAIN
#undef STEP_PRE
#undef BSEL0
#undef BSEL1
#undef COMPUTE
#undef STAGE

  // epilogue
  float sc[4], of[4];
#pragma unroll
  for (int nt = 0; nt < 4; ++nt) {
    const int oc = oc0 + wn * 64 + nt * 16 + col;
    sc[nt] = e0[oc];
    of[nt] = BN ? e1[oc] : 0.f;
  }
  if (BN) {
#pragma unroll
    for (int mt = 0; mt < 4; ++mt)
#pragma unroll
      for (int r = 0; r < 4; ++r) {
        const int px = wm * 64 + mt * 16 + quad * 4 + r;
        const int y = ty + (px >> 4), x = tx + (px & 15);
        unsigned short* rowp =
            out16 + (((size_t)b * HP + y + 1) * HP + x + 1) * 256 + oc0 + wn * 64 + col;
#pragma unroll
        for (int nt = 0; nt < 4; ++nt)
          rowp[nt * 16] = f2bf(acc[mt][nt][r] * sc[nt] + of[nt]);
      }
  } else {
    // fused channel l2norm: this block owns ALL 128 output channels per px
    float part[4][4];
#pragma unroll
    for (int mt = 0; mt < 4; ++mt)
#pragma unroll
      for (int r = 0; r < 4; ++r) {
        float s = 0.f;
#pragma unroll
        for (int nt = 0; nt < 4; ++nt) {
          const float v = acc[mt][nt][r] + sc[nt];
          s += v * v;
        }
        part[mt][r] = s;
      }
#pragma unroll
    for (int msk = 1; msk < 16; msk <<= 1)
#pragma unroll
      for (int mt = 0; mt < 4; ++mt)
#pragma unroll
        for (int r = 0; r < 4; ++r)
          part[mt][r] += __shfl_xor(part[mt][r], msk, 64);
    if (col == 0) {
#pragma unroll
      for (int mt = 0; mt < 4; ++mt)
#pragma unroll
        for (int r = 0; r < 4; ++r)
          nrm[wm * 64 + mt * 16 + quad * 4 + r][wn] = part[mt][r];
    }
    __syncthreads();
#pragma unroll
    for (int mt = 0; mt < 4; ++mt)
#pragma unroll
      for (int r = 0; r < 4; ++r) {
        const int px = wm * 64 + mt * 16 + quad * 4 + r;
        const int y = ty + (px >> 4), x = tx + (px & 15);
        const float nn = nrm[px][0] + nrm[px][1];
        const float rn = 1.f / fmaxf(sqrtf(nn), 1e-12f);
        unsigned short* rowp =
            out16 + (((size_t)b * Hh + y) * Ww + x) * 128 + wn * 64 + col;
#pragma unroll
        for (int nt = 0; nt < 4; ++nt)
          rowp[nt * 16] = f2bf((acc[mt][nt][r] + sc[nt]) * rn);
      }
  }
}

// distinct names so rocprof rows distinguish conv1 vs conv2
__global__ __launch_bounds__(256) void conv1_mfma(
    const unsigned short* __restrict__ in, const unsigned short* __restrict__ wt,
    const float* __restrict__ e0, const float* __restrict__ e1,
    unsigned short* __restrict__ out16) {
  conv3x3_body<256, true>(in, wt, e0, e1, out16);
}
__global__ __launch_bounds__(256) void conv2_mfma(
    const unsigned short* __restrict__ in, const unsigned short* __restrict__ wt,
    const float* __restrict__ e0, const float* __restrict__ e1,
    unsigned short* __restrict__ out16) {
  conv3x3_body<128, false>(in, wt, e0, e1, out16);
}

// ---------------------------------------------------------------------------
// 4x4 transpose across lanes differing in bits 0..1 (regs r0..r3)
__device__ inline void xpose4(float& r0, float& r1, float& r2, float& r3,
                              int lane) {
  const int b1 = (lane >> 1) & 1, b0 = lane & 1;
  float s0 = b1 ? r0 : r2;
  float s1 = b1 ? r1 : r3;
  s0 = __shfl_xor(s0, 2, 64);
  s1 = __shfl_xor(s1, 2, 64);
  if (b1) { r0 = s0; r1 = s1; } else { r2 = s0; r3 = s1; }
  float t0 = b0 ? r0 : r1;
  float t1 = b0 ? r2 : r3;
  t0 = __shfl_xor(t0, 1, 64);
  t1 = __shfl_xor(t1, 1, 64);
  if (b0) { r0 = t0; r2 = t1; } else { r1 = t0; r3 = t1; }
}

// Score: MFMA GEMM (64 px x 320 reps, K=128) + fused epilogue, no LDS.
// Rep order: n = cls*4 + {pos, neg0, neg1, neg2}. Wave w covers n in
// [w*80, w*80+80) as 5 n-tiles of 16.
__global__ __launch_bounds__(256) void score_mfma(
    const unsigned short* __restrict__ embb, const unsigned short* __restrict__ Rb,
    float* __restrict__ out) {
  const int px0 = blockIdx.x * 64;
  const int b = blockIdx.y;
  const int t = threadIdx.x;
  const int lane = t & 63, w = t >> 6;
  const int quad = lane >> 4, col = lane & 15;
  const int n0 = w * 80;
  const unsigned short* Abase = embb + ((size_t)b * PIX + px0) * 128;

  f32x4 acc[4][5];
#pragma unroll
  for (int mt = 0; mt < 4; ++mt)
#pragma unroll
    for (int nt = 0; nt < 5; ++nt) acc[mt][nt] = {0.f, 0.f, 0.f, 0.f};

#pragma unroll
  for (int ks = 0; ks < 4; ++ks) {
    bf16x8 bf[5], af[4];
#pragma unroll
    for (int nt = 0; nt < 5; ++nt)
      bf[nt] = *(const bf16x8*)(Rb + (size_t)(n0 + nt * 16 + col) * 128 +
                                ks * 32 + quad * 8);
#pragma unroll
    for (int mt = 0; mt < 4; ++mt)
      af[mt] = *(const bf16x8*)(Abase + (size_t)(mt * 16 + col) * 128 +
                                ks * 32 + quad * 8);
#pragma unroll
    for (int mt = 0; mt < 4; ++mt)
#pragma unroll
      for (int nt = 0; nt < 5; ++nt)
        acc[mt][nt] = __builtin_amdgcn_mfma_f32_16x16x32_bf16(
            af[mt], bf[nt], acc[mt][nt], 0, 0, 0);
  }

  const int j = lane & 3, kq = (lane >> 2) & 3;
#pragma unroll
  for (int mt = 0; mt < 4; ++mt) {
    const int px = px0 + mt * 16 + quad * 4 + j;
#pragma unroll
    for (int nt = 0; nt < 5; ++nt) {
      float v0 = acc[mt][nt][0], v1 = acc[mt][nt][1];
      float v2 = acc[mt][nt][2], v3 = acc[mt][nt][3];
      xpose4(v0, v1, v2, v3, lane);
      // lane now holds (dp, dn0, dn1, dn2) for (px, cls)
      const int gc = w * 20 + nt * 4 + kq;
      const float d2p = fmaxf(2.f - 2.f * v0, 0.f);
      const float dist = sqrtf(d2p);
      const float q0 = fmaxf(2.f - 2.f * v1, 0.f);
      const float q1 = fmaxf(2.f - 2.f * v2, 0.f);
      const float q2 = fmaxf(2.f - 2.f * v3, 0.f);
      const float dn0 = sqrtf(q0), dn1 = sqrtf(q1), dn2 = sqrtf(q2);
      const float pn = __expf(-2.f * fminf(q0, fminf(q1, q2)));
      const float pori = __expf(-2.f * d2p);
      const float minn = fminf(dn0, fminf(dn1, dn2));
      const float shifted = dist + 0.3f * fmaxf(2.0f - minn, 0.f);
      const float p = __expf(-2.f * shifted * shifted);
      const float clsv = __logf(fmaxf(p, 1e-5f) / fmaxf(1.f - p, 1e-5f));
      const size_t bc = ((size_t)b * NCLS + gc) * PIX + px;
      out[O0 + bc] = clsv;
      out[O1 + bc] = pn;
      out[O2 + bc] = dist;
      out[O4 + bc] = pori;
      const size_t b3 = (((size_t)b * NCLS + gc) * 3) * PIX + px;
      out[O3 + b3] = dn0;
      out[O3 + b3 + PIX] = dn1;
      out[O3 + b3 + 2 * PIX] = dn2;
    }
  }
}

// ---------------------------------------------------------------------------
extern "C" void kernel_launch(void* const* d_in, const int* in_sizes, int n_in,
                              void* d_out, int out_size, void* d_ws,
                              size_t ws_size, hipStream_t stream) {
  const float* x = (const float*)d_in[0];
  const float* w1 = (const float*)d_in[1];
  const float* c1b = (const float*)d_in[2];
  const float* g = (const float*)d_in[3];
  const float* be = (const float*)d_in[4];
  const float* mu = (const float*)d_in[5];
  const float* var = (const float*)d_in[6];
  const float* w2 = (const float*)d_in[7];
  const float* c2b = (const float*)d_in[8];
  const float* rw = (const float*)d_in[9];
  const float* rb = (const float*)d_in[10];
  const float* nw = (const float*)d_in[11];
  const float* nb = (const float*)d_in[12];
  float* out = (float*)d_out;

  unsigned short* xp = (unsigned short*)d_ws;   // bf16 padded NHWC input
  unsigned short* hp = xp + XP_ELEMS;           // bf16 padded NHWC hidden
  unsigned short* wt1 = hp + XP_ELEMS;          // 589,824 bf16
  unsigned short* wt2 = wt1 + 589824;           // 294,912 bf16
  float* bns = (float*)(wt2 + 294912);
  float* bno = bns + 256;
  float* rpv = bno + 256;                       // 10,240 fp32
  unsigned short* Rb = (unsigned short*)(rpv + 10240);  // 40,960 bf16
  unsigned short* embb = xp;                    // alias: xp dead after conv1

  hipMemsetAsync(xp, 0, XP_ELEMS * sizeof(unsigned short), stream);
  hipMemsetAsync(hp, 0, XP_ELEMS * sizeof(unsigned short), stream);
  pad_x_kernel<<<dim3(3, Hh, Bz), 256, 0, stream>>>(x, xp);
  prep_w_kernel<<<2304, 256, 0, stream>>>(w1, w2, c1b, g, be, mu, var, wt1, wt2,
                                          bns, bno);
  rep_norm_kernel<<<NCLS, 128, 0, stream>>>(rw, rb, rpv, Rb);
  mlp_neg_kernel<<<dim3(NCLS, 3), 128, 0, stream>>>(rpv, nw, nb, Rb);
  conv1_mfma<<<dim3(72, 2, Bz), 256, 0, stream>>>(xp, wt1, bns, bno, hp);
  conv2_mfma<<<dim3(72, 1, Bz), 256, 0, stream>>>(hp, wt2, c2b, nullptr, embb);
  score_mfma<<<dim3(144, Bz), 256, 0, stream>>>(embb, Rb, out);
}

// Round 7
// 498.473 us; speedup vs baseline: 1.7695x; 1.1286x over previous
//
#include <hip/hip_runtime.h>
#include <cstddef>
#include <cstdint>

// Problem constants
constexpr int Bz = 8, CIN = 256, Hh = 96, Ww = 96;
constexpr int EMB1 = 256, EMB2 = 128, NCLS = 80;
constexpr int HP = 98; // padded spatial
constexpr size_t PIX = (size_t)Hh * Ww;                 // 9216
constexpr size_t XP_ELEMS = (size_t)Bz * HP * HP * CIN; // 19,668,992 bf16 elems

// Output layout (flat concat, fp32)
constexpr size_t O0 = 0;                       // cls_score      (B,80,96,96)
constexpr size_t O1 = (size_t)Bz * NCLS * PIX; // cls_score_neg
constexpr size_t O2 = 2 * O1;                  // distances
constexpr size_t O3 = 3 * O1;                  // distances_neg  (B,80,3,96,96)
constexpr size_t O4 = 6 * O1;                  // probs_ori

typedef short bf16x8 __attribute__((ext_vector_type(8)));
typedef float f32x4 __attribute__((ext_vector_type(4)));

__device__ inline unsigned short f2bf(float f) {
  union { float f; unsigned int u; } v; v.f = f;
  unsigned int r = v.u + 0x7fffu + ((v.u >> 16) & 1u);
  return (unsigned short)(r >> 16);
}

// async global->LDS, 16B per lane; offset arg MUST be 0 (R4/R5 lesson:
// nonzero imm corrupts the LDS destination). Offsets go in the pointer.
#define GLD16(gp, lp)                                              \
  __builtin_amdgcn_global_load_lds(                                \
      (__attribute__((address_space(1))) void*)((void*)(gp)),      \
      (__attribute__((address_space(3))) void*)(lp), 16, 0, 0)

// Counted-wait + barrier as ONE asm with memory clobber (raw s_barrier is
// not a compiler fence); sched_barrier(0) pins the MIR scheduler.
#define WAIT_BAR(n)                                                       \
  do {                                                                    \
    asm volatile("s_waitcnt vmcnt(" #n ")\n\ts_barrier" ::: "memory");    \
    __builtin_amdgcn_sched_barrier(0);                                    \
  } while (0)

// ---------------------------------------------------------------------------
// Prep: x (NCHW fp32) -> padded NHWC bf16 interior (borders via memset).
__global__ __launch_bounds__(256) void pad_x_kernel(const float* __restrict__ x,
                                                    unsigned short* __restrict__ xp) {
  __shared__ float tile[32][257];
  const int b = blockIdx.z, y = blockIdx.y, x0 = blockIdx.x * 32;
  const int t = threadIdx.x;
  const int px = t & 31, cg = t >> 5;  // 8 channel groups
  const float* src = x + (((size_t)b * CIN) * Hh + y) * Ww + x0 + px;
#pragma unroll 4
  for (int c = cg; c < CIN; c += 8)
    tile[px][c] = src[(size_t)c * Hh * Ww];
  __syncthreads();
  unsigned short* orow =
      xp + (((size_t)b * HP + y + 1) * HP + (x0 + 1)) * 256 + t;
#pragma unroll 4
  for (int p = 0; p < 32; ++p)
    orow[(size_t)p * 256] = f2bf(tile[p][t]);
}

// Prep: weights -> bf16 in MFMA-FRAGMENT order + BN fold.
// Layout: wtf[s=tap*8+c8][f=oc/16][quad=chsub][oc16][ch8]; a wave's bf[nt]
// fragment is ONE coalesced 1KB block (lane l=quad*16+col at byte l*16).
__global__ __launch_bounds__(256) void prep_w_kernel(
    const float* __restrict__ w1, const float* __restrict__ w2,
    const float* __restrict__ c1b, const float* __restrict__ g,
    const float* __restrict__ be, const float* __restrict__ mu,
    const float* __restrict__ var, unsigned short* __restrict__ wt1,
    unsigned short* __restrict__ wt2, float* __restrict__ bns,
    float* __restrict__ bno) {
  const int e = blockIdx.x * 256 + threadIdx.x;
  if (e < 9 * 256 * 256) {  // wt1, OC=256 (16 frags of 16 oc per step)
    const int cc = e & 7, col = (e >> 3) & 15, quad = (e >> 7) & 3;
    const int f = (e >> 9) & 15, s = e >> 13;
    const int tap = s >> 3, c8 = s & 7;
    const int ic = c8 * 32 + quad * 8 + cc, oc = f * 16 + col;
    wt1[e] = f2bf(w1[((size_t)(oc * 256 + ic)) * 9 + tap]);
  }
  if (e < 9 * 128 * 256) {  // wt2, OC=128 (8 frags per step)
    const int cc = e & 7, col = (e >> 3) & 15, quad = (e >> 7) & 3;
    const int f = (e >> 9) & 7, s = e >> 12;
    const int tap = s >> 3, c8 = s & 7;
    const int ic = c8 * 32 + quad * 8 + cc, oc = f * 16 + col;
    wt2[e] = f2bf(w2[((size_t)(oc * 256 + ic)) * 9 + tap]);
  }
  if (e < 256) {
    const float s = g[e] * rsqrtf(var[e] + 1e-5f);
    bns[e] = s;
    bno[e] = (c1b[e] - mu[e]) * s + be[e];
  }
}

// reps = l2norm(rep_w[:,0] + rep_b) per class (80 x 128); fp32 rpv + bf16 Rb
__global__ __launch_bounds__(128) void rep_norm_kernel(const float* __restrict__ rw,
                                                       const float* __restrict__ rb,
                                                       float* __restrict__ r,
                                                       unsigned short* __restrict__ Rb) {
  __shared__ float red[2];
  const int c = blockIdx.x, t = threadIdx.x;
  const float v = rw[c * 128 + t] + rb[c * 128 + t];
  float s = v * v;
  for (int msk = 1; msk < 64; msk <<= 1) s += __shfl_xor(s, msk, 64);
  if ((t & 63) == 0) red[t >> 6] = s;
  __syncthreads();
  const float ss = red[0] + red[1];
  const float rn = 1.f / fmaxf(sqrtf(ss), 1e-12f);
  r[c * 128 + t] = v * rn;
  Rb[(size_t)(c * 4) * 128 + t] = f2bf(v * rn);  // rep slot v=0 (positive)
}

// reps_neg: per (class, neg) 3-layer MLP on r, then l2norm -> bf16 Rb slot
__global__ __launch_bounds__(128) void mlp_neg_kernel(const float* __restrict__ r,
                                                      const float* __restrict__ W,
                                                      const float* __restrict__ bb,
                                                      unsigned short* __restrict__ Rb) {
  __shared__ float h0[128], h1[128];
  __shared__ float red[2];
  const int c = blockIdx.x, ng = blockIdx.y, t = threadIdx.x;
  h0[t] = r[c * 128 + t];
  __syncthreads();
  float s = 0.f;
  for (int lay = 0; lay < 3; ++lay) {
    const float* hin = (lay & 1) ? h1 : h0;
    float* hout = (lay & 1) ? h0 : h1;
    const float* wr = W + (((size_t)ng * 3 + lay) * 128 + t) * 128;
    s = bb[(ng * 3 + lay) * 128 + t];
    for (int e = 0; e < 128; ++e) s += wr[e] * hin[e];
    if (lay < 2) hout[t] = fmaxf(s, 0.f);
    __syncthreads();
  }
  float q = s * s;
  for (int msk = 1; msk < 64; msk <<= 1) q += __shfl_xor(q, msk, 64);
  if ((t & 63) == 0) red[t >> 6] = q;
  __syncthreads();
  const float ss = red[0] + red[1];
  const float rn = 1.f / fmaxf(sqrtf(ss), 1e-12f);
  Rb[((size_t)(c * 4) + 1 + ng) * 128 + t] = f2bf(s * rn);
}

// ---------------------------------------------------------------------------
// bf16 MFMA implicit-GEMM 3x3 conv, NHWC (padded input HPxHP, IC=256).
// LDS-BW-relief version: only A goes through LDS (3-buffer ring, GLD16);
// B is loaded DIRECTLY global->VGPR from the fragment-ordered weight array
// (1 coalesced 1KB load per fragment, L2-resident), double-buffered one
// step ahead in registers (bfA/bfB). Per block-step LDS traffic drops
// 48KB -> 24KB and B-side bank conflicts vanish.
// Sync: step u: [vmcnt(6)+s_barrier][load B(u+1) 4x][stage A(u+2) 2xGLD16]
//               [compute buf u%3]. The 6 survivors = exactly step-u's issue
// set, so all of step u-1's ops (incl. A(u+1) staging) are retired at every
// barrier; compiler auto-waitcnts cover the bf register dependencies.
// BN=true: out bf16 padded NHWC (B,98,98,256) at (y+1,x+1), v=acc*e0+e1
// BN=false: out bf16 NHWC (B,96,96,128), v=l2norm_c(acc+e0) (fused l2norm)
template <int OC, bool BN>
__device__ __forceinline__ void conv3x3_body(
    const unsigned short* __restrict__ in, const unsigned short* __restrict__ wt,
    const float* __restrict__ e0, const float* __restrict__ e1,
    unsigned short* __restrict__ out16) {
  __shared__ unsigned short smA[3][128 * 32];  // 3 x 8KB [px][k]
  __shared__ float nrm[128][2];                // l2norm partials (BN=false)
  const int tile = blockIdx.x;                 // 0..71
  const int oc0 = blockIdx.y * 128;
  const int b = blockIdx.z;
  const int ty = (tile / 6) * 8, tx = (tile % 6) * 16;
  const int t = threadIdx.x;
  const int lane = t & 63, w = t >> 6;
  const int wm = w & 1, wn = w >> 1;
  const int quad = lane >> 4, col = lane & 15;
  const int chl = (lane & 3) * 8;              // A staging channel sub-offset

  // per-lane A staging bases (ky=0, kx=0, ch=0)
  size_t baseA0, baseA1;
  {
    const int px0 = (w * 2 + 0) * 16 + (lane >> 2);
    const int px1 = (w * 2 + 1) * 16 + (lane >> 2);
    baseA0 = (((size_t)b * HP + ty + (px0 >> 4)) * HP + tx + (px0 & 15)) * 256 + chl;
    baseA1 = (((size_t)b * HP + ty + (px1 >> 4)) * HP + tx + (px1 & 15)) * 256 + chl;
  }

  // wave-uniform LDS staging destinations / per-lane read base
  char* const dA0 = (char*)smA + (w * 2 + 0) * 1024;
  char* const dA1 = (char*)smA + (w * 2 + 1) * 1024;
  const char* const ldsA = (const char*)smA + (wm * 64 + col) * 64 + quad * 16;

  // B fragment base: frag index = oc0/16 + wn*4 + nt; within-frag lane*8 elems
  const unsigned short* Bb = wt + (size_t)oc0 * 32 + wn * 2048 + lane * 8;

  f32x4 acc[4][4];
#pragma unroll
  for (int mt = 0; mt < 4; ++mt)
#pragma unroll
    for (int nt = 0; nt < 4; ++nt) acc[mt][nt] = {0.f, 0.f, 0.f, 0.f};

  bf16x8 bA0, bA1, bA2, bA3, bB0, bB1, bB2, bB3;

#define LOADB(D0, D1, D2, D3, SREL)                                        \
  do {                                                                     \
    const unsigned short* _p = Bb + (size_t)(SREL) * (OC * 32);            \
    D0 = *(const bf16x8*)(_p + 0);                                         \
    D1 = *(const bf16x8*)(_p + 512);                                       \
    D2 = *(const bf16x8*)(_p + 1024);                                      \
    D3 = *(const bf16x8*)(_p + 1536);                                      \
  } while (0)

#define COMPUTE(BUF, B0, B1, B2, B3)                                         \
  do {                                                                       \
    bf16x8 af0 = *(const bf16x8*)(ldsA + (BUF) * 8192 + 0);                  \
    bf16x8 af1 = *(const bf16x8*)(ldsA + (BUF) * 8192 + 1024);               \
    bf16x8 af2 = *(const bf16x8*)(ldsA + (BUF) * 8192 + 2048);               \
    bf16x8 af3 = *(const bf16x8*)(ldsA + (BUF) * 8192 + 3072);               \
    __builtin_amdgcn_s_setprio(1);                                           \
    acc[0][0] = __builtin_amdgcn_mfma_f32_16x16x32_bf16(af0, B0, acc[0][0], 0, 0, 0); \
    acc[0][1] = __builtin_amdgcn_mfma_f32_16x16x32_bf16(af0, B1, acc[0][1], 0, 0, 0); \
    acc[0][2] = __builtin_amdgcn_mfma_f32_16x16x32_bf16(af0, B2, acc[0][2], 0, 0, 0); \
    acc[0][3] = __builtin_amdgcn_mfma_f32_16x16x32_bf16(af0, B3, acc[0][3], 0, 0, 0); \
    acc[1][0] = __builtin_amdgcn_mfma_f32_16x16x32_bf16(af1, B0, acc[1][0], 0, 0, 0); \
    acc[1][1] = __builtin_amdgcn_mfma_f32_16x16x32_bf16(af1, B1, acc[1][1], 0, 0, 0); \
    acc[1][2] = __builtin_amdgcn_mfma_f32_16x16x32_bf16(af1, B2, acc[1][2], 0, 0, 0); \
    acc[1][3] = __builtin_amdgcn_mfma_f32_16x16x32_bf16(af1, B3, acc[1][3], 0, 0, 0); \
    acc[2][0] = __builtin_amdgcn_mfma_f32_16x16x32_bf16(af2, B0, acc[2][0], 0, 0, 0); \
    acc[2][1] = __builtin_amdgcn_mfma_f32_16x16x32_bf16(af2, B1, acc[2][1], 0, 0, 0); \
    acc[2][2] = __builtin_amdgcn_mfma_f32_16x16x32_bf16(af2, B2, acc[2][2], 0, 0, 0); \
    acc[2][3] = __builtin_amdgcn_mfma_f32_16x16x32_bf16(af2, B3, acc[2][3], 0, 0, 0); \
    acc[3][0] = __builtin_amdgcn_mfma_f32_16x16x32_bf16(af3, B0, acc[3][0], 0, 0, 0); \
    acc[3][1] = __builtin_amdgcn_mfma_f32_16x16x32_bf16(af3, B1, acc[3][1], 0, 0, 0); \
    acc[3][2] = __builtin_amdgcn_mfma_f32_16x16x32_bf16(af3, B2, acc[3][2], 0, 0, 0); \
    acc[3][3] = __builtin_amdgcn_mfma_f32_16x16x32_bf16(af3, B3, acc[3][3], 0, 0, 0); \
    __builtin_amdgcn_s_setprio(0);                                           \
  } while (0)

// main steps R in [0,22): load B(R+1), stage A(R+2) from current-row bases
#define STEP(R, C0, C1, C2, C3, N0, N1, N2, N3)                         \
  do {                                                                  \
    WAIT_BAR(6);                                                        \
    LOADB(N0, N1, N2, N3, (R) + 1);                                     \
    GLD16(Acur0 + ((R) + 2) * 32, dA0 + (((R) + 2) % 3) * 8192);        \
    GLD16(Acur1 + ((R) + 2) * 32, dA1 + (((R) + 2) % 3) * 8192);        \
    COMPUTE((R) % 3, C0, C1, C2, C3);                                   \
  } while (0)
// steps 22,23: stage next ky-row's steps 0,1 (if any)
#define STEP_PRE(R, C0, C1, C2, C3, N0, N1, N2, N3)                     \
  do {                                                                  \
    if ((R) == 23 && ky == 2) { WAIT_BAR(0); } else { WAIT_BAR(6); }    \
    if (ky < 2 || (R) < 23) LOADB(N0, N1, N2, N3, (R) + 1);             \
    if (ky < 2) {                                                       \
      GLD16(An0 + ((R) - 22) * 32, dA0 + (((R) + 2) % 3) * 8192);       \
      GLD16(An1 + ((R) - 22) * 32, dA1 + (((R) + 2) % 3) * 8192);       \
    }                                                                   \
    COMPUTE((R) % 3, C0, C1, C2, C3);                                   \
  } while (0)

  // pointer init (ky = 0)
  const unsigned short* Acur0 = in + baseA0;
  const unsigned short* Acur1 = in + baseA1;
  const unsigned short* An0 = Acur0 + HP * 256;
  const unsigned short* An1 = Acur1 + HP * 256;

  // prologue: stage A(0),A(1); load B(0); drain once
  GLD16(Acur0, dA0 + 0 * 8192);
  GLD16(Acur1, dA1 + 0 * 8192);
  GLD16(Acur0 + 32, dA0 + 1 * 8192);
  GLD16(Acur1 + 32, dA1 + 1 * 8192);
  LOADB(bA0, bA1, bA2, bA3, 0);
  WAIT_BAR(0);

  for (int ky = 0; ky < 3; ++ky) {
    STEP(0, bA0, bA1, bA2, bA3, bB0, bB1, bB2, bB3);
    STEP(1, bB0, bB1, bB2, bB3, bA0, bA1, bA2, bA3);
    STEP(2, bA0, bA1, bA2, bA3, bB0, bB1, bB2, bB3);
    STEP(3, bB0, bB1, bB2, bB3, bA0, bA1, bA2, bA3);
    STEP(4, bA0, bA1, bA2, bA3, bB0, bB1, bB2, bB3);
    STEP(5, bB0, bB1, bB2, bB3, bA0, bA1, bA2, bA3);
    STEP(6, bA0, bA1, bA2, bA3, bB0, bB1, bB2, bB3);
    STEP(7, bB0, bB1, bB2, bB3, bA0, bA1, bA2, bA3);
    STEP(8, bA0, bA1, bA2, bA3, bB0, bB1, bB2, bB3);
    STEP(9, bB0, bB1, bB2, bB3, bA0, bA1, bA2, bA3);
    STEP(10, bA0, bA1, bA2, bA3, bB0, bB1, bB2, bB3);
    STEP(11, bB0, bB1, bB2, bB3, bA0, bA1, bA2, bA3);
    STEP(12, bA0, bA1, bA2, bA3, bB0, bB1, bB2, bB3);
    STEP(13, bB0, bB1, bB2, bB3, bA0, bA1, bA2, bA3);
    STEP(14, bA0, bA1, bA2, bA3, bB0, bB1, bB2, bB3);
    STEP(15, bB0, bB1, bB2, bB3, bA0, bA1, bA2, bA3);
    STEP(16, bA0, bA1, bA2, bA3, bB0, bB1, bB2, bB3);
    STEP(17, bB0, bB1, bB2, bB3, bA0, bA1, bA2, bA3);
    STEP(18, bA0, bA1, bA2, bA3, bB0, bB1, bB2, bB3);
    STEP(19, bB0, bB1, bB2, bB3, bA0, bA1, bA2, bA3);
    STEP(20, bA0, bA1, bA2, bA3, bB0, bB1, bB2, bB3);
    STEP(21, bB0, bB1, bB2, bB3, bA0, bA1, bA2, bA3);
    STEP_PRE(22, bA0, bA1, bA2, bA3, bB0, bB1, bB2, bB3);
    STEP_PRE(23, bB0, bB1, bB2, bB3, bA0, bA1, bA2, bA3);
    Bb += 24 * (OC * 32);  // B layout linear in step index
    if (ky < 2) {
      Acur0 = An0; Acur1 = An1;
      An0 += HP * 256; An1 += HP * 256;
    }
  }
#undef STEP
#undef STEP_PRE
#undef COMPUTE
#undef LOADB

  // epilogue
  float sc[4], of[4];
#pragma unroll
  for (int nt = 0; nt < 4; ++nt) {
    const int oc = oc0 + wn * 64 + nt * 16 + col;
    sc[nt] = e0[oc];
    of[nt] = BN ? e1[oc] : 0.f;
  }
  if (BN) {
#pragma unroll
    for (int mt = 0; mt < 4; ++mt)
#pragma unroll
      for (int r = 0; r < 4; ++r) {
        const int px = wm * 64 + mt * 16 + quad * 4 + r;
        const int y = ty + (px >> 4), x = tx + (px & 15);
        unsigned short* rowp =
            out16 + (((size_t)b * HP + y + 1) * HP + x + 1) * 256 + oc0 + wn * 64 + col;
#pragma unroll
        for (int nt = 0; nt < 4; ++nt)
          rowp[nt * 16] = f2bf(acc[mt][nt][r] * sc[nt] + of[nt]);
      }
  } else {
    // fused channel l2norm: this block owns ALL 128 output channels per px
    float part[4][4];
#pragma unroll
    for (int mt = 0; mt < 4; ++mt)
#pragma unroll
      for (int r = 0; r < 4; ++r) {
        float s = 0.f;
#pragma unroll
        for (int nt = 0; nt < 4; ++nt) {
          const float v = acc[mt][nt][r] + sc[nt];
          s += v * v;
        }
        part[mt][r] = s;
      }
#pragma unroll
    for (int msk = 1; msk < 16; msk <<= 1)
#pragma unroll
      for (int mt = 0; mt < 4; ++mt)
#pragma unroll
        for (int r = 0; r < 4; ++r)
          part[mt][r] += __shfl_xor(part[mt][r], msk, 64);
    if (col == 0) {
#pragma unroll
      for (int mt = 0; mt < 4; ++mt)
#pragma unroll
        for (int r = 0; r < 4; ++r)
          nrm[wm * 64 + mt * 16 + quad * 4 + r][wn] = part[mt][r];
    }
    __syncthreads();
#pragma unroll
    for (int mt = 0; mt < 4; ++mt)
#pragma unroll
      for (int r = 0; r < 4; ++r) {
        const int px = wm * 64 + mt * 16 + quad * 4 + r;
        const int y = ty + (px >> 4), x = tx + (px & 15);
        const float nn = nrm[px][0] + nrm[px][1];
        const float rn = 1.f / fmaxf(sqrtf(nn), 1e-12f);
        unsigned short* rowp =
            out16 + (((size_t)b * Hh + y) * Ww + x) * 128 + wn * 64 + col;
#pragma unroll
        for (int nt = 0; nt < 4; ++nt)
          rowp[nt * 16] = f2bf((acc[mt][nt][r] + sc[nt]) * rn);
      }
  }
}

// distinct names so rocprof rows distinguish conv1 vs conv2
__global__ __launch_bounds__(256) void conv1_mfma(
    const unsigned short* __restrict__ in, const unsigned short* __restrict__ wt,
    const float* __restrict__ e0, const float* __restrict__ e1,
    unsigned short* __restrict__ out16) {
  conv3x3_body<256, true>(in, wt, e0, e1, out16);
}
__global__ __launch_bounds__(256) void conv2_mfma(
    const unsigned short* __restrict__ in, const unsigned short* __restrict__ wt,
    const float* __restrict__ e0, const float* __restrict__ e1,
    unsigned short* __restrict__ out16) {
  conv3x3_body<128, false>(in, wt, e0, e1, out16);
}

// ---------------------------------------------------------------------------
// 4x4 transpose across lanes differing in bits 0..1 (regs r0..r3)
__device__ inline void xpose4(float& r0, float& r1, float& r2, float& r3,
                              int lane) {
  const int b1 = (lane >> 1) & 1, b0 = lane & 1;
  float s0 = b1 ? r0 : r2;
  float s1 = b1 ? r1 : r3;
  s0 = __shfl_xor(s0, 2, 64);
  s1 = __shfl_xor(s1, 2, 64);
  if (b1) { r0 = s0; r1 = s1; } else { r2 = s0; r3 = s1; }
  float t0 = b0 ? r0 : r1;
  float t1 = b0 ? r2 : r3;
  t0 = __shfl_xor(t0, 1, 64);
  t1 = __shfl_xor(t1, 1, 64);
  if (b0) { r0 = t0; r2 = t1; } else { r1 = t0; r3 = t1; }
}

// Score: MFMA GEMM (64 px x 320 reps, K=128) + fused epilogue, no LDS.
// Rep order: n = cls*4 + {pos, neg0, neg1, neg2}. Wave w covers n in
// [w*80, w*80+80) as 5 n-tiles of 16.
__global__ __launch_bounds__(256) void score_mfma(
    const unsigned short* __restrict__ embb, const unsigned short* __restrict__ Rb,
    float* __restrict__ out) {
  const int px0 = blockIdx.x * 64;
  const int b = blockIdx.y;
  const int t = threadIdx.x;
  const int lane = t & 63, w = t >> 6;
  const int quad = lane >> 4, col = lane & 15;
  const int n0 = w * 80;
  const unsigned short* Abase = embb + ((size_t)b * PIX + px0) * 128;

  f32x4 acc[4][5];
#pragma unroll
  for (int mt = 0; mt < 4; ++mt)
#pragma unroll
    for (int nt = 0; nt < 5; ++nt) acc[mt][nt] = {0.f, 0.f, 0.f, 0.f};

#pragma unroll
  for (int ks = 0; ks < 4; ++ks) {
    bf16x8 bf[5], af[4];
#pragma unroll
    for (int nt = 0; nt < 5; ++nt)
      bf[nt] = *(const bf16x8*)(Rb + (size_t)(n0 + nt * 16 + col) * 128 +
                                ks * 32 + quad * 8);
#pragma unroll
    for (int mt = 0; mt < 4; ++mt)
      af[mt] = *(const bf16x8*)(Abase + (size_t)(mt * 16 + col) * 128 +
                                ks * 32 + quad * 8);
#pragma unroll
    for (int mt = 0; mt < 4; ++mt)
#pragma unroll
      for (int nt = 0; nt < 5; ++nt)
        acc[mt][nt] = __builtin_amdgcn_mfma_f32_16x16x32_bf16(
            af[mt], bf[nt], acc[mt][nt], 0, 0, 0);
  }

  const int j = lane & 3, kq = (lane >> 2) & 3;
#pragma unroll
  for (int mt = 0; mt < 4; ++mt) {
    const int px = px0 + mt * 16 + quad * 4 + j;
#pragma unroll
    for (int nt = 0; nt < 5; ++nt) {
      float v0 = acc[mt][nt][0], v1 = acc[mt][nt][1];
      float v2 = acc[mt][nt][2], v3 = acc[mt][nt][3];
      xpose4(v0, v1, v2, v3, lane);
      // lane now holds (dp, dn0, dn1, dn2) for (px, cls)
      const int gc = w * 20 + nt * 4 + kq;
      const float d2p = fmaxf(2.f - 2.f * v0, 0.f);
      const float dist = sqrtf(d2p);
      const float q0 = fmaxf(2.f - 2.f * v1, 0.f);
      const float q1 = fmaxf(2.f - 2.f * v2, 0.f);
      const float q2 = fmaxf(2.f - 2.f * v3, 0.f);
      const float dn0 = sqrtf(q0), dn1 = sqrtf(q1), dn2 = sqrtf(q2);
      const float pn = __expf(-2.f * fminf(q0, fminf(q1, q2)));
      const float pori = __expf(-2.f * d2p);
      const float minn = fminf(dn0, fminf(dn1, dn2));
      const float shifted = dist + 0.3f * fmaxf(2.0f - minn, 0.f);
      const float p = __expf(-2.f * shifted * shifted);
      const float clsv = __logf(fmaxf(p, 1e-5f) / fmaxf(1.f - p, 1e-5f));
      const size_t bc = ((size_t)b * NCLS + gc) * PIX + px;
      out[O0 + bc] = clsv;
      out[O1 + bc] = pn;
      out[O2 + bc] = dist;
      out[O4 + bc] = pori;
      const size_t b3 = (((size_t)b * NCLS + gc) * 3) * PIX + px;
      out[O3 + b3] = dn0;
      out[O3 + b3 + PIX] = dn1;
      out[O3 + b3 + 2 * PIX] = dn2;
    }
  }
}

// ---------------------------------------------------------------------------
extern "C" void kernel_launch(void* const* d_in, const int* in_sizes, int n_in,
                              void* d_out, int out_size, void* d_ws,
                              size_t ws_size, hipStream_t stream) {
  const float* x = (const float*)d_in[0];
  const float* w1 = (const float*)d_in[1];
  const float* c1b = (const float*)d_in[2];
  const float* g = (const float*)d_in[3];
  const float* be = (const float*)d_in[4];
  const float* mu = (const float*)d_in[5];
  const float* var = (const float*)d_in[6];
  const float* w2 = (const float*)d_in[7];
  const float* c2b = (const float*)d_in[8];
  const float* rw = (const float*)d_in[9];
  const float* rb = (const float*)d_in[10];
  const float* nw = (const float*)d_in[11];
  const float* nb = (const float*)d_in[12];
  float* out = (float*)d_out;

  unsigned short* xp = (unsigned short*)d_ws;   // bf16 padded NHWC input
  unsigned short* hp = xp + XP_ELEMS;           // bf16 padded NHWC hidden
  unsigned short* wt1 = hp + XP_ELEMS;          // 589,824 bf16 (frag order)
  unsigned short* wt2 = wt1 + 589824;           // 294,912 bf16 (frag order)
  float* bns = (float*)(wt2 + 294912);
  float* bno = bns + 256;
  float* rpv = bno + 256;                       // 10,240 fp32
  unsigned short* Rb = (unsigned short*)(rpv + 10240);  // 40,960 bf16
  unsigned short* embb = xp;                    // alias: xp dead after conv1

  hipMemsetAsync(xp, 0, XP_ELEMS * sizeof(unsigned short), stream);
  hipMemsetAsync(hp, 0, XP_ELEMS * sizeof(unsigned short), stream);
  pad_x_kernel<<<dim3(3, Hh, Bz), 256, 0, stream>>>(x, xp);
  prep_w_kernel<<<2304, 256, 0, stream>>>(w1, w2, c1b, g, be, mu, var, wt1, wt2,
                                          bns, bno);
  rep_norm_kernel<<<NCLS, 128, 0, stream>>>(rw, rb, rpv, Rb);
  mlp_neg_kernel<<<dim3(NCLS, 3), 128, 0, stream>>>(rpv, nw, nb, Rb);
  conv1_mfma<<<dim3(72, 2, Bz), 256, 0, stream>>>(xp, wt1, bns, bno, hp);
  conv2_mfma<<<dim3(72, 1, Bz), 256, 0, stream>>>(hp, wt2, c2b, nullptr, embb);
  score_mfma<<<dim3(144, Bz), 256, 0, stream>>>(embb, Rb, out);
}